// Round 1
// baseline (407.785 us; speedup 1.0000x reference)
//
#include <hip/hip_runtime.h>

// KernelizedHeadAttention, B=4 S=1024 D=2048 H=16 DH=128 DHID=128 DKER=64
// Strategy: bf16 MFMA everywhere; single-pass merge (no online max needed):
//   out[s] = [ sum_t (m? score+eps : exp(saw)) * v[t] ] / (rowsum_s + eps + exp(lse_s))

typedef __bf16 bf16_t;
typedef __attribute__((ext_vector_type(8))) __bf16 bf16x8;
typedef __attribute__((ext_vector_type(4))) float f32x4;

#define MFMA(a, b, c) __builtin_amdgcn_mfma_f32_16x16x32_bf16((a), (b), (c), 0, 0, 0)

static __device__ __forceinline__ float gelu_exact(float x) {
    return 0.5f * x * (1.0f + erff(x * 0.70710678118654752f));
}

// ---------------- weights: convert f32 -> bf16, transposed for B-fragments ----------------
__global__ __launch_bounds__(256) void conv_weights_kernel(
    const float* __restrict__ wq1, const float* __restrict__ wk1,
    const float* __restrict__ wq2, const float* __restrict__ wk2,
    const float* __restrict__ iK,
    bf16_t* __restrict__ wq1t, bf16_t* __restrict__ wk1t,
    bf16_t* __restrict__ wq2t, bf16_t* __restrict__ wk2t,
    bf16_t* __restrict__ iKt)
{
    const int idx = blockIdx.x * 256 + threadIdx.x;
    if (idx < 16 * 128 * 128) {           // [h][e][d] <- [h][d][e]
        int h = idx >> 14, e = (idx >> 7) & 127, d = idx & 127;
        wq1t[idx] = (bf16_t)wq1[(h << 14) + (d << 7) + e];
        wk1t[idx] = (bf16_t)wk1[(h << 14) + (d << 7) + e];
    }
    if (idx < 16 * 64 * 128) {            // [h][f][e] <- [h][e][f]
        int h = idx >> 13, f = (idx >> 7) & 63, e = idx & 127;
        wq2t[idx] = (bf16_t)wq2[(h << 13) + (e << 6) + f];
        wk2t[idx] = (bf16_t)wk2[(h << 13) + (e << 6) + f];
    }
    if (idx < 16 * 64 * 64) {             // [h][g][f] <- [h][f][g]
        int h = idx >> 12, g = (idx >> 6) & 63, f = idx & 63;
        iKt[idx] = (bf16_t)iK[(h << 12) + (f << 6) + g];
    }
}

// ---------------- V: [B,S,H,128] f32 -> vT [B,H,128,S] bf16 (LDS-tiled transpose) --------
__global__ __launch_bounds__(256) void conv_v_kernel(
    const float* __restrict__ v, bf16_t* __restrict__ vT)
{
    __shared__ bf16_t tr[128][72];
    const int bh = blockIdx.x, b = bh >> 4, h = bh & 15;
    const int t0 = blockIdx.y * 64;
    const int tid = threadIdx.x;
#pragma unroll
    for (int i = 0; i < 8; ++i) {
        int f4 = tid + 256 * i;                 // 2048 float4 = 64 t x 128 d
        int t = f4 >> 5, c4 = f4 & 31;
        const float4 vv = *reinterpret_cast<const float4*>(
            &v[((size_t)b * 1024 + t0 + t) * 2048 + h * 128 + c4 * 4]);
        tr[c4 * 4 + 0][t] = (bf16_t)vv.x;
        tr[c4 * 4 + 1][t] = (bf16_t)vv.y;
        tr[c4 * 4 + 2][t] = (bf16_t)vv.z;
        tr[c4 * 4 + 3][t] = (bf16_t)vv.w;
    }
    __syncthreads();
#pragma unroll
    for (int i = 0; i < 32; ++i) {
        int e = tid + 256 * i;                  // 8192 bf16
        int d = e >> 6, tl = e & 63;
        vT[((size_t)bh * 128 + d) * 1024 + t0 + tl] = tr[d][tl];
    }
}

// ---------------- feature maps: qf = |gelu(gelu(q W1) W2)|, kf path w/ interaction ------
__global__ __launch_bounds__(256) void feat_kernel(
    const float* __restrict__ q, const float* __restrict__ k,
    const bf16_t* __restrict__ wq1t, const bf16_t* __restrict__ wq2t,
    const bf16_t* __restrict__ wk1t, const bf16_t* __restrict__ wk2t,
    const bf16_t* __restrict__ iKt,
    const float* __restrict__ sD, const float* __restrict__ sD2,
    bf16_t* __restrict__ qf, bf16_t* __restrict__ kf)
{
    __shared__ bf16_t xa[64][136];
    __shared__ bf16_t h1[64][136];
    __shared__ bf16_t k2[64][72];

    const int tid = threadIdx.x;
    const int lane = tid & 63, w = tid >> 6;
    const int lr = lane & 15, lg = lane >> 4;
    const int row0 = blockIdx.x * 64;          // token rows over B*S=4096
    const int h = blockIdx.y;
    const int path = blockIdx.z;               // 0 = q, 1 = k

    const float* X = path ? k : q;
    const bf16_t* w1t = path ? wk1t : wq1t;
    const bf16_t* w2t = path ? wk2t : wq2t;
    bf16_t* outp = path ? kf : qf;

#pragma unroll
    for (int i = 0; i < 8; ++i) {              // stage X tile [64][128] -> LDS bf16
        int f4 = tid + 256 * i;
        int r = f4 >> 5, c4 = f4 & 31;
        const float4 vv = *reinterpret_cast<const float4*>(
            &X[(size_t)(row0 + r) * 2048 + h * 128 + c4 * 4]);
        xa[r][c4 * 4 + 0] = (bf16_t)vv.x;
        xa[r][c4 * 4 + 1] = (bf16_t)vv.y;
        xa[r][c4 * 4 + 2] = (bf16_t)vv.z;
        xa[r][c4 * 4 + 3] = (bf16_t)vv.w;
    }
    __syncthreads();

    // stage 1: [64x128] @ W1[128x128] -> gelu -> h1
    bf16x8 a1[4];
#pragma unroll
    for (int kk = 0; kk < 4; ++kk)
        a1[kk] = *reinterpret_cast<const bf16x8*>(&xa[w * 16 + lr][kk * 32 + lg * 8]);
#pragma unroll
    for (int nt = 0; nt < 8; ++nt) {
        f32x4 acc = {0.f, 0.f, 0.f, 0.f};
#pragma unroll
        for (int kk = 0; kk < 4; ++kk) {
            bf16x8 bfr = *reinterpret_cast<const bf16x8*>(
                &w1t[(size_t)h * 16384 + (nt * 16 + lr) * 128 + kk * 32 + lg * 8]);
            acc = MFMA(a1[kk], bfr, acc);
        }
#pragma unroll
        for (int r = 0; r < 4; ++r)
            h1[w * 16 + lg * 4 + r][nt * 16 + lr] = (bf16_t)gelu_exact(acc[r]);
    }
    __syncthreads();

    // stage 2: [64x128] @ W2[128x64]
    bf16x8 a2[4];
#pragma unroll
    for (int kk = 0; kk < 4; ++kk)
        a2[kk] = *reinterpret_cast<const bf16x8*>(&h1[w * 16 + lr][kk * 32 + lg * 8]);

    if (path == 0) {
#pragma unroll
        for (int nt = 0; nt < 4; ++nt) {
            f32x4 acc = {0.f, 0.f, 0.f, 0.f};
#pragma unroll
            for (int kk = 0; kk < 4; ++kk) {
                bf16x8 bfr = *reinterpret_cast<const bf16x8*>(
                    &w2t[(size_t)h * 8192 + (nt * 16 + lr) * 128 + kk * 32 + lg * 8]);
                acc = MFMA(a2[kk], bfr, acc);
            }
#pragma unroll
            for (int r = 0; r < 4; ++r) {
                int n = row0 + w * 16 + lg * 4 + r;
                int bb = n >> 10, s = n & 1023;
                outp[(((size_t)bb * 16 + h) * 1024 + s) * 64 + nt * 16 + lr] =
                    (bf16_t)fabsf(gelu_exact(acc[r]));
            }
        }
    } else {
#pragma unroll
        for (int nt = 0; nt < 4; ++nt) {
            f32x4 acc = {0.f, 0.f, 0.f, 0.f};
#pragma unroll
            for (int kk = 0; kk < 4; ++kk) {
                bf16x8 bfr = *reinterpret_cast<const bf16x8*>(
                    &w2t[(size_t)h * 8192 + (nt * 16 + lr) * 128 + kk * 32 + lg * 8]);
                acc = MFMA(a2[kk], bfr, acc);
            }
#pragma unroll
            for (int r = 0; r < 4; ++r) {
                int f = nt * 16 + lr;
                k2[w * 16 + lg * 4 + r][f] =
                    (bf16_t)(fabsf(sD[h * 64 + f]) * gelu_exact(acc[r]));
            }
        }
        __syncthreads();
        // stage 3: kf = |kf2 + (kf2 @ interK) * sD2|
        bf16x8 a3[2];
#pragma unroll
        for (int kk = 0; kk < 2; ++kk)
            a3[kk] = *reinterpret_cast<const bf16x8*>(&k2[w * 16 + lr][kk * 32 + lg * 8]);
#pragma unroll
        for (int nt = 0; nt < 4; ++nt) {
            f32x4 acc = {0.f, 0.f, 0.f, 0.f};
#pragma unroll
            for (int kk = 0; kk < 2; ++kk) {
                bf16x8 bfr = *reinterpret_cast<const bf16x8*>(
                    &iKt[(size_t)h * 4096 + (nt * 16 + lr) * 64 + kk * 32 + lg * 8]);
                acc = MFMA(a3[kk], bfr, acc);
            }
#pragma unroll
            for (int r = 0; r < 4; ++r) {
                int row = w * 16 + lg * 4 + r;
                int g = nt * 16 + lr;
                float base = (float)k2[row][g];
                float kv = fabsf(base + acc[r] * sD2[h * 64 + g]);
                int n = row0 + row;
                int bb = n >> 10, s = n & 1023;
                outp[(((size_t)bb * 16 + h) * 1024 + s) * 64 + g] = (bf16_t)kv;
            }
        }
    }
}

// ---------------- fused attention: scores -> merge -> PV, single pass -------------------
__global__ __launch_bounds__(256) void attn_kernel(
    const bf16_t* __restrict__ qf, const bf16_t* __restrict__ kf,
    const bf16_t* __restrict__ vT,
    const unsigned char* __restrict__ mask8,
    const float* __restrict__ saw, const float* __restrict__ lse,
    float* __restrict__ out)
{
    __shared__ bf16_t p[64][72];
    __shared__ int mflag;

    const int tid = threadIdx.x;
    const int lane = tid & 63, w = tid >> 6;
    const int lr = lane & 15, lg = lane >> 4;
    const int s0 = blockIdx.x * 64;
    const int bh = blockIdx.y;
    const int b = bh >> 4, h = bh & 15;

    if (tid == 0) {   // detect mask storage width: int32 => bytes 4i+1 all zero
        unsigned a = 0;
        for (int i = 0; i < 64; ++i) a |= mask8[4 * i + 1];
        mflag = (a == 0) ? 1 : 0;
    }
    __syncthreads();
    const bool mask_is_int = (mflag != 0);
    const int* mask32 = (const int*)mask8;

    bf16x8 aq0, aq1;
    {
        const size_t qb = ((size_t)bh * 1024 + s0 + w * 16 + lr) * 64;
        aq0 = *reinterpret_cast<const bf16x8*>(&qf[qb + lg * 8]);
        aq1 = *reinterpret_cast<const bf16x8*>(&qf[qb + 32 + lg * 8]);
    }

    const f32x4 fzero = {0.f, 0.f, 0.f, 0.f};
    f32x4 oacc[8];
#pragma unroll
    for (int i = 0; i < 8; ++i) oacc[i] = fzero;
    float rowsum[4] = {0.f, 0.f, 0.f, 0.f};

    const size_t sawb = (size_t)bh << 20;
    const size_t mb = (size_t)b << 20;

    for (int t0 = 0; t0 < 1024; t0 += 64) {
        // QK^T for this wave's 16 rows x 64 t-cols
        f32x4 c[4];
#pragma unroll
        for (int nt = 0; nt < 4; ++nt) {
            f32x4 acc = fzero;
            const size_t kb = ((size_t)bh * 1024 + t0 + nt * 16 + lr) * 64;
            bf16x8 b0 = *reinterpret_cast<const bf16x8*>(&kf[kb + lg * 8]);
            bf16x8 b1 = *reinterpret_cast<const bf16x8*>(&kf[kb + 32 + lg * 8]);
            acc = MFMA(aq0, b0, acc);
            acc = MFMA(aq1, b1, acc);
            c[nt] = acc;
        }
        // elementwise merge -> P (bf16) in LDS; accumulate masked rowsum
#pragma unroll
        for (int nt = 0; nt < 4; ++nt) {
#pragma unroll
            for (int r = 0; r < 4; ++r) {
                const int srow = s0 + w * 16 + lg * 4 + r;
                const int tcol = t0 + nt * 16 + lr;
                const size_t e = (size_t)srow * 1024 + tcol;
                unsigned mv = mask_is_int ? (unsigned)mask32[mb + e]
                                          : (unsigned)mask8[mb + e];
                float sc = c[nt][r];
                float ev = __expf(saw[sawb + e]);
                float wv = mv ? (sc + 1e-6f) : ev;
                rowsum[r] += mv ? sc : 0.f;
                p[w * 16 + lg * 4 + r][nt * 16 + lr] = (bf16_t)wv;
            }
        }
        asm volatile("s_waitcnt lgkmcnt(0)" ::: "memory");
        __builtin_amdgcn_sched_barrier(0);
        // PV: rows of P are this wave's own rows only (no cross-wave LDS sharing)
        bf16x8 ap0 = *reinterpret_cast<const bf16x8*>(&p[w * 16 + lr][lg * 8]);
        bf16x8 ap1 = *reinterpret_cast<const bf16x8*>(&p[w * 16 + lr][32 + lg * 8]);
#pragma unroll
        for (int dt = 0; dt < 8; ++dt) {
            const size_t vb = ((size_t)bh * 128 + dt * 16 + lr) * 1024 + t0;
            bf16x8 b0 = *reinterpret_cast<const bf16x8*>(&vT[vb + lg * 8]);
            bf16x8 b1 = *reinterpret_cast<const bf16x8*>(&vT[vb + 32 + lg * 8]);
            oacc[dt] = MFMA(ap0, b0, oacc[dt]);
            oacc[dt] = MFMA(ap1, b1, oacc[dt]);
        }
    }

    // reduce rowsum across the 16 cols held by lanes sharing lg
#pragma unroll
    for (int r = 0; r < 4; ++r) {
        float s = rowsum[r];
#pragma unroll
        for (int m = 1; m < 16; m <<= 1) s += __shfl_xor(s, m);
        rowsum[r] = s;
    }
    float invden[4];
#pragma unroll
    for (int r = 0; r < 4; ++r) {
        const int srow = s0 + w * 16 + lg * 4 + r;
        invden[r] = 1.0f / (rowsum[r] + 1e-6f + __expf(lse[(size_t)bh * 1024 + srow]));
    }
#pragma unroll
    for (int dt = 0; dt < 8; ++dt) {
#pragma unroll
        for (int r = 0; r < 4; ++r) {
            const int srow = s0 + w * 16 + lg * 4 + r;
            out[((size_t)b * 1024 + srow) * 2048 + h * 128 + dt * 16 + lr] =
                oacc[dt][r] * invden[r];
        }
    }
}

extern "C" void kernel_launch(void* const* d_in, const int* in_sizes, int n_in,
                              void* d_out, int out_size, void* d_ws, size_t ws_size,
                              hipStream_t stream)
{
    const float* q   = (const float*)d_in[0];
    const float* k   = (const float*)d_in[1];
    const float* v   = (const float*)d_in[2];
    const unsigned char* mask = (const unsigned char*)d_in[3];
    const float* lse = (const float*)d_in[4];
    const float* saw = (const float*)d_in[5];
    const float* wq1 = (const float*)d_in[6];
    const float* wk1 = (const float*)d_in[7];
    const float* wq2 = (const float*)d_in[8];
    const float* wk2 = (const float*)d_in[9];
    const float* iK  = (const float*)d_in[10];
    const float* sD  = (const float*)d_in[11];
    const float* sD2 = (const float*)d_in[12];
    float* out = (float*)d_out;

    bf16_t* wsb  = (bf16_t*)d_ws;
    bf16_t* wq1t = wsb;                    // 16*128*128 = 262144
    bf16_t* wk1t = wq1t + 262144;
    bf16_t* wq2t = wk1t + 262144;          // 16*64*128 = 131072
    bf16_t* wk2t = wq2t + 131072;
    bf16_t* iKt  = wk2t + 131072;          // 16*64*64  = 65536
    bf16_t* qf   = iKt  + 65536;           // 4*16*1024*64 = 4194304
    bf16_t* kf   = qf   + 4194304;
    bf16_t* vT   = kf   + 4194304;         // 4*16*128*1024 = 8388608
    // total ws use: ~35.3 MB

    conv_weights_kernel<<<dim3(1024), dim3(256), 0, stream>>>(
        wq1, wk1, wq2, wk2, iK, wq1t, wk1t, wq2t, wk2t, iKt);
    conv_v_kernel<<<dim3(64, 16), dim3(256), 0, stream>>>(v, vT);
    feat_kernel<<<dim3(64, 16, 2), dim3(256), 0, stream>>>(
        q, k, wq1t, wq2t, wk1t, wk2t, iKt, sD, sD2, qf, kf);
    attn_kernel<<<dim3(16, 64), dim3(256), 0, stream>>>(
        qf, kf, vT, mask, saw, lse, out);
}

// Round 2
// 389.005 us; speedup vs baseline: 1.0483x; 1.0483x over previous
//
#include <hip/hip_runtime.h>

// KernelizedHeadAttention, B=4 S=1024 D=2048 H=16 DH=128 DHID=128 DKER=64
// Strategy: bf16 MFMA everywhere; single-pass merge (no online max needed):
//   out[s] = [ sum_t (m? score+eps : exp(saw)) * v[t] ] / (rowsum_s + eps + exp(lse_s))
// R2: register-prefetch (double-buffered) the 256MB saw stream one t-tile ahead.

typedef __bf16 bf16_t;
typedef __attribute__((ext_vector_type(8))) __bf16 bf16x8;
typedef __attribute__((ext_vector_type(4))) float f32x4;

#define MFMA(a, b, c) __builtin_amdgcn_mfma_f32_16x16x32_bf16((a), (b), (c), 0, 0, 0)

static __device__ __forceinline__ float gelu_exact(float x) {
    return 0.5f * x * (1.0f + erff(x * 0.70710678118654752f));
}

// ---------------- weights: convert f32 -> bf16, transposed for B-fragments ----------------
__global__ __launch_bounds__(256) void conv_weights_kernel(
    const float* __restrict__ wq1, const float* __restrict__ wk1,
    const float* __restrict__ wq2, const float* __restrict__ wk2,
    const float* __restrict__ iK,
    bf16_t* __restrict__ wq1t, bf16_t* __restrict__ wk1t,
    bf16_t* __restrict__ wq2t, bf16_t* __restrict__ wk2t,
    bf16_t* __restrict__ iKt)
{
    const int idx = blockIdx.x * 256 + threadIdx.x;
    if (idx < 16 * 128 * 128) {           // [h][e][d] <- [h][d][e]
        int h = idx >> 14, e = (idx >> 7) & 127, d = idx & 127;
        wq1t[idx] = (bf16_t)wq1[(h << 14) + (d << 7) + e];
        wk1t[idx] = (bf16_t)wk1[(h << 14) + (d << 7) + e];
    }
    if (idx < 16 * 64 * 128) {            // [h][f][e] <- [h][e][f]
        int h = idx >> 13, f = (idx >> 7) & 63, e = idx & 127;
        wq2t[idx] = (bf16_t)wq2[(h << 13) + (e << 6) + f];
        wk2t[idx] = (bf16_t)wk2[(h << 13) + (e << 6) + f];
    }
    if (idx < 16 * 64 * 64) {             // [h][g][f] <- [h][f][g]
        int h = idx >> 12, g = (idx >> 6) & 63, f = idx & 63;
        iKt[idx] = (bf16_t)iK[(h << 12) + (f << 6) + g];
    }
}

// ---------------- V: [B,S,H,128] f32 -> vT [B,H,128,S] bf16 (LDS-tiled transpose) --------
__global__ __launch_bounds__(256) void conv_v_kernel(
    const float* __restrict__ v, bf16_t* __restrict__ vT)
{
    __shared__ bf16_t tr[128][72];
    const int bh = blockIdx.x, b = bh >> 4, h = bh & 15;
    const int t0 = blockIdx.y * 64;
    const int tid = threadIdx.x;
#pragma unroll
    for (int i = 0; i < 8; ++i) {
        int f4 = tid + 256 * i;                 // 2048 float4 = 64 t x 128 d
        int t = f4 >> 5, c4 = f4 & 31;
        const float4 vv = *reinterpret_cast<const float4*>(
            &v[((size_t)b * 1024 + t0 + t) * 2048 + h * 128 + c4 * 4]);
        tr[c4 * 4 + 0][t] = (bf16_t)vv.x;
        tr[c4 * 4 + 1][t] = (bf16_t)vv.y;
        tr[c4 * 4 + 2][t] = (bf16_t)vv.z;
        tr[c4 * 4 + 3][t] = (bf16_t)vv.w;
    }
    __syncthreads();
#pragma unroll
    for (int i = 0; i < 32; ++i) {
        int e = tid + 256 * i;                  // 8192 bf16
        int d = e >> 6, tl = e & 63;
        vT[((size_t)bh * 128 + d) * 1024 + t0 + tl] = tr[d][tl];
    }
}

// ---------------- feature maps: qf = |gelu(gelu(q W1) W2)|, kf path w/ interaction ------
__global__ __launch_bounds__(256) void feat_kernel(
    const float* __restrict__ q, const float* __restrict__ k,
    const bf16_t* __restrict__ wq1t, const bf16_t* __restrict__ wq2t,
    const bf16_t* __restrict__ wk1t, const bf16_t* __restrict__ wk2t,
    const bf16_t* __restrict__ iKt,
    const float* __restrict__ sD, const float* __restrict__ sD2,
    bf16_t* __restrict__ qf, bf16_t* __restrict__ kf)
{
    __shared__ bf16_t xa[64][136];
    __shared__ bf16_t h1[64][136];
    __shared__ bf16_t k2[64][72];

    const int tid = threadIdx.x;
    const int lane = tid & 63, w = tid >> 6;
    const int lr = lane & 15, lg = lane >> 4;
    const int row0 = blockIdx.x * 64;          // token rows over B*S=4096
    const int h = blockIdx.y;
    const int path = blockIdx.z;               // 0 = q, 1 = k

    const float* X = path ? k : q;
    const bf16_t* w1t = path ? wk1t : wq1t;
    const bf16_t* w2t = path ? wk2t : wq2t;
    bf16_t* outp = path ? kf : qf;

#pragma unroll
    for (int i = 0; i < 8; ++i) {              // stage X tile [64][128] -> LDS bf16
        int f4 = tid + 256 * i;
        int r = f4 >> 5, c4 = f4 & 31;
        const float4 vv = *reinterpret_cast<const float4*>(
            &X[(size_t)(row0 + r) * 2048 + h * 128 + c4 * 4]);
        xa[r][c4 * 4 + 0] = (bf16_t)vv.x;
        xa[r][c4 * 4 + 1] = (bf16_t)vv.y;
        xa[r][c4 * 4 + 2] = (bf16_t)vv.z;
        xa[r][c4 * 4 + 3] = (bf16_t)vv.w;
    }
    __syncthreads();

    // stage 1: [64x128] @ W1[128x128] -> gelu -> h1
    bf16x8 a1[4];
#pragma unroll
    for (int kk = 0; kk < 4; ++kk)
        a1[kk] = *reinterpret_cast<const bf16x8*>(&xa[w * 16 + lr][kk * 32 + lg * 8]);
#pragma unroll
    for (int nt = 0; nt < 8; ++nt) {
        f32x4 acc = {0.f, 0.f, 0.f, 0.f};
#pragma unroll
        for (int kk = 0; kk < 4; ++kk) {
            bf16x8 bfr = *reinterpret_cast<const bf16x8*>(
                &w1t[(size_t)h * 16384 + (nt * 16 + lr) * 128 + kk * 32 + lg * 8]);
            acc = MFMA(a1[kk], bfr, acc);
        }
#pragma unroll
        for (int r = 0; r < 4; ++r)
            h1[w * 16 + lg * 4 + r][nt * 16 + lr] = (bf16_t)gelu_exact(acc[r]);
    }
    __syncthreads();

    // stage 2: [64x128] @ W2[128x64]
    bf16x8 a2[4];
#pragma unroll
    for (int kk = 0; kk < 4; ++kk)
        a2[kk] = *reinterpret_cast<const bf16x8*>(&h1[w * 16 + lr][kk * 32 + lg * 8]);

    if (path == 0) {
#pragma unroll
        for (int nt = 0; nt < 4; ++nt) {
            f32x4 acc = {0.f, 0.f, 0.f, 0.f};
#pragma unroll
            for (int kk = 0; kk < 4; ++kk) {
                bf16x8 bfr = *reinterpret_cast<const bf16x8*>(
                    &w2t[(size_t)h * 8192 + (nt * 16 + lr) * 128 + kk * 32 + lg * 8]);
                acc = MFMA(a2[kk], bfr, acc);
            }
#pragma unroll
            for (int r = 0; r < 4; ++r) {
                int n = row0 + w * 16 + lg * 4 + r;
                int bb = n >> 10, s = n & 1023;
                outp[(((size_t)bb * 16 + h) * 1024 + s) * 64 + nt * 16 + lr] =
                    (bf16_t)fabsf(gelu_exact(acc[r]));
            }
        }
    } else {
#pragma unroll
        for (int nt = 0; nt < 4; ++nt) {
            f32x4 acc = {0.f, 0.f, 0.f, 0.f};
#pragma unroll
            for (int kk = 0; kk < 4; ++kk) {
                bf16x8 bfr = *reinterpret_cast<const bf16x8*>(
                    &w2t[(size_t)h * 8192 + (nt * 16 + lr) * 128 + kk * 32 + lg * 8]);
                acc = MFMA(a2[kk], bfr, acc);
            }
#pragma unroll
            for (int r = 0; r < 4; ++r) {
                int f = nt * 16 + lr;
                k2[w * 16 + lg * 4 + r][f] =
                    (bf16_t)(fabsf(sD[h * 64 + f]) * gelu_exact(acc[r]));
            }
        }
        __syncthreads();
        // stage 3: kf = |kf2 + (kf2 @ interK) * sD2|
        bf16x8 a3[2];
#pragma unroll
        for (int kk = 0; kk < 2; ++kk)
            a3[kk] = *reinterpret_cast<const bf16x8*>(&k2[w * 16 + lr][kk * 32 + lg * 8]);
#pragma unroll
        for (int nt = 0; nt < 4; ++nt) {
            f32x4 acc = {0.f, 0.f, 0.f, 0.f};
#pragma unroll
            for (int kk = 0; kk < 2; ++kk) {
                bf16x8 bfr = *reinterpret_cast<const bf16x8*>(
                    &iKt[(size_t)h * 4096 + (nt * 16 + lr) * 64 + kk * 32 + lg * 8]);
                acc = MFMA(a3[kk], bfr, acc);
            }
#pragma unroll
            for (int r = 0; r < 4; ++r) {
                int row = w * 16 + lg * 4 + r;
                int g = nt * 16 + lr;
                float base = (float)k2[row][g];
                float kv = fabsf(base + acc[r] * sD2[h * 64 + g]);
                int n = row0 + row;
                int bb = n >> 10, s = n & 1023;
                outp[(((size_t)bb * 16 + h) * 1024 + s) * 64 + g] = (bf16_t)kv;
            }
        }
    }
}

// ---------------- fused attention: scores -> merge -> PV, single pass -------------------
// Per t-tile phase with saw prefetched one tile ahead into the NXT register set.
#define PROCESS_TILE(T0, CUR, NXT, TNEXT)                                        \
  {                                                                              \
    f32x4 c[4];                                                                  \
    _Pragma("unroll")                                                            \
    for (int nt = 0; nt < 4; ++nt) {                                             \
      f32x4 acc = fzero;                                                         \
      const size_t kb = ((size_t)bh * 1024 + (T0) + nt * 16 + lr) * 64;          \
      bf16x8 kb0 = *reinterpret_cast<const bf16x8*>(&kf[kb + lg * 8]);           \
      bf16x8 kb1 = *reinterpret_cast<const bf16x8*>(&kf[kb + 32 + lg * 8]);      \
      acc = MFMA(aq0, kb0, acc);                                                 \
      acc = MFMA(aq1, kb1, acc);                                                 \
      c[nt] = acc;                                                               \
    }                                                                            \
    /* issue next tile's saw loads now; consumed one full phase later */         \
    _Pragma("unroll")                                                            \
    for (int nt = 0; nt < 4; ++nt) {                                             \
      _Pragma("unroll")                                                          \
      for (int r = 0; r < 4; ++r)                                                \
        NXT[nt * 4 + r] = sawp[(size_t)r * 1024 + nt * 16 + (TNEXT)];            \
    }                                                                            \
    _Pragma("unroll")                                                            \
    for (int nt = 0; nt < 4; ++nt) {                                             \
      _Pragma("unroll")                                                          \
      for (int r = 0; r < 4; ++r) {                                              \
        const size_t e = (size_t)(lrow + r) * 1024 + (T0) + nt * 16 + lcol;      \
        unsigned mv = mask_is_int ? (unsigned)mask32[mb + e]                     \
                                  : (unsigned)mask8[mb + e];                     \
        float sc = c[nt][r];                                                     \
        float wv = mv ? (sc + 1e-6f) : __expf(CUR[nt * 4 + r]);                  \
        rowsum[r] += mv ? sc : 0.f;                                              \
        p[w * 16 + lg * 4 + r][nt * 16 + lr] = (bf16_t)wv;                       \
      }                                                                          \
    }                                                                            \
    asm volatile("s_waitcnt lgkmcnt(0)" ::: "memory");                           \
    __builtin_amdgcn_sched_barrier(0);                                           \
    bf16x8 ap0 = *reinterpret_cast<const bf16x8*>(&p[w * 16 + lr][lg * 8]);      \
    bf16x8 ap1 = *reinterpret_cast<const bf16x8*>(&p[w * 16 + lr][32 + lg * 8]); \
    _Pragma("unroll")                                                            \
    for (int dt = 0; dt < 8; ++dt) {                                             \
      const size_t vb = ((size_t)bh * 128 + dt * 16 + lr) * 1024 + (T0);         \
      bf16x8 vb0 = *reinterpret_cast<const bf16x8*>(&vT[vb + lg * 8]);           \
      bf16x8 vb1 = *reinterpret_cast<const bf16x8*>(&vT[vb + 32 + lg * 8]);      \
      oacc[dt] = MFMA(ap0, vb0, oacc[dt]);                                       \
      oacc[dt] = MFMA(ap1, vb1, oacc[dt]);                                       \
    }                                                                            \
  }

__global__ __launch_bounds__(256) void attn_kernel(
    const bf16_t* __restrict__ qf, const bf16_t* __restrict__ kf,
    const bf16_t* __restrict__ vT,
    const unsigned char* __restrict__ mask8,
    const float* __restrict__ saw, const float* __restrict__ lse,
    float* __restrict__ out)
{
    __shared__ bf16_t p[64][72];
    __shared__ int mflag;

    const int tid = threadIdx.x;
    const int lane = tid & 63, w = tid >> 6;
    const int lr = lane & 15, lg = lane >> 4;
    const int s0 = blockIdx.x * 64;
    const int bh = blockIdx.y;
    const int b = bh >> 4, h = bh & 15;

    if (tid == 0) {   // detect mask storage width: int32 => bytes 4i+1 all zero
        unsigned a = 0;
        for (int i = 0; i < 64; ++i) a |= mask8[4 * i + 1];
        mflag = (a == 0) ? 1 : 0;
    }
    __syncthreads();
    const bool mask_is_int = (mflag != 0);
    const int* mask32 = (const int*)mask8;

    bf16x8 aq0, aq1;
    {
        const size_t qb = ((size_t)bh * 1024 + s0 + w * 16 + lr) * 64;
        aq0 = *reinterpret_cast<const bf16x8*>(&qf[qb + lg * 8]);
        aq1 = *reinterpret_cast<const bf16x8*>(&qf[qb + 32 + lg * 8]);
    }

    const f32x4 fzero = {0.f, 0.f, 0.f, 0.f};
    f32x4 oacc[8];
#pragma unroll
    for (int i = 0; i < 8; ++i) oacc[i] = fzero;
    float rowsum[4] = {0.f, 0.f, 0.f, 0.f};

    const size_t sawb = (size_t)bh << 20;
    const size_t mb = (size_t)b << 20;
    const int lrow = s0 + w * 16 + lg * 4;      // this lane's first s-row
    const int lcol = lr;                        // this lane's t-col within a 16-group
    const float* sawp = &saw[sawb + (size_t)lrow * 1024 + lcol];

    float sA[16], sB[16];
    // prologue: prefetch tile 0 into A
#pragma unroll
    for (int nt = 0; nt < 4; ++nt)
#pragma unroll
        for (int r = 0; r < 4; ++r)
            sA[nt * 4 + r] = sawp[(size_t)r * 1024 + nt * 16];

    for (int tt = 0; tt < 8; ++tt) {
        const int t0 = tt * 128;
        PROCESS_TILE(t0,      sA, sB, t0 + 64);
        PROCESS_TILE(t0 + 64, sB, sA, (t0 + 128) & 1023);   // wrap keeps last load in-bounds
    }

    // reduce rowsum across the 16 cols held by lanes sharing lg
#pragma unroll
    for (int r = 0; r < 4; ++r) {
        float s = rowsum[r];
#pragma unroll
        for (int m = 1; m < 16; m <<= 1) s += __shfl_xor(s, m);
        rowsum[r] = s;
    }
    float invden[4];
#pragma unroll
    for (int r = 0; r < 4; ++r) {
        const int srow = s0 + w * 16 + lg * 4 + r;
        invden[r] = 1.0f / (rowsum[r] + 1e-6f + __expf(lse[(size_t)bh * 1024 + srow]));
    }
#pragma unroll
    for (int dt = 0; dt < 8; ++dt) {
#pragma unroll
        for (int r = 0; r < 4; ++r) {
            const int srow = s0 + w * 16 + lg * 4 + r;
            out[((size_t)b * 1024 + srow) * 2048 + h * 128 + dt * 16 + lr] =
                oacc[dt][r] * invden[r];
        }
    }
}

extern "C" void kernel_launch(void* const* d_in, const int* in_sizes, int n_in,
                              void* d_out, int out_size, void* d_ws, size_t ws_size,
                              hipStream_t stream)
{
    const float* q   = (const float*)d_in[0];
    const float* k   = (const float*)d_in[1];
    const float* v   = (const float*)d_in[2];
    const unsigned char* mask = (const unsigned char*)d_in[3];
    const float* lse = (const float*)d_in[4];
    const float* saw = (const float*)d_in[5];
    const float* wq1 = (const float*)d_in[6];
    const float* wk1 = (const float*)d_in[7];
    const float* wq2 = (const float*)d_in[8];
    const float* wk2 = (const float*)d_in[9];
    const float* iK  = (const float*)d_in[10];
    const float* sD  = (const float*)d_in[11];
    const float* sD2 = (const float*)d_in[12];
    float* out = (float*)d_out;

    bf16_t* wsb  = (bf16_t*)d_ws;
    bf16_t* wq1t = wsb;                    // 16*128*128 = 262144
    bf16_t* wk1t = wq1t + 262144;
    bf16_t* wq2t = wk1t + 262144;          // 16*64*128 = 131072
    bf16_t* wk2t = wq2t + 131072;
    bf16_t* iKt  = wk2t + 131072;          // 16*64*64  = 65536
    bf16_t* qf   = iKt  + 65536;           // 4*16*1024*64 = 4194304
    bf16_t* kf   = qf   + 4194304;
    bf16_t* vT   = kf   + 4194304;         // 4*16*128*1024 = 8388608
    // total ws use: ~35.3 MB

    conv_weights_kernel<<<dim3(1024), dim3(256), 0, stream>>>(
        wq1, wk1, wq2, wk2, iK, wq1t, wk1t, wq2t, wk2t, iKt);
    conv_v_kernel<<<dim3(64, 16), dim3(256), 0, stream>>>(v, vT);
    feat_kernel<<<dim3(64, 16, 2), dim3(256), 0, stream>>>(
        q, k, wq1t, wq2t, wk1t, wk2t, iKt, sD, sD2, qf, kf);
    attn_kernel<<<dim3(16, 64), dim3(256), 0, stream>>>(
        qf, kf, vT, mask, saw, lse, out);
}